// Round 1
// baseline (448.620 us; speedup 1.0000x reference)
//
#include <hip/hip_runtime.h>
#include <math.h>

// ---------------------------------------------------------------------------
// SLADGNN: 3-layer GCN + prototype distance head + MLP readout (fp32 exact).
// Strategy: build CSR (by dst) once per launch, reuse for all 3 aggregations.
// Transform-then-aggregate so aggregation dim is the (smaller) output dim.
// ---------------------------------------------------------------------------

__global__ void zero_int_kernel(int* __restrict__ p, int n) {
    int i = blockIdx.x * 256 + threadIdx.x;
    if (i < n) p[i] = 0;
}

__global__ void count_kernel(const int* __restrict__ ei, int E, int* __restrict__ deg) {
    int e = blockIdx.x * 256 + threadIdx.x;
    if (e < E) atomicAdd(&deg[ei[E + e]], 1);   // dst = ei[1][e]
}

// Per-block exclusive scan of deg -> row_ptr (intra-block), block sums out.
__global__ void scan_block_kernel(const int* __restrict__ deg, int N,
                                  int* __restrict__ row_ptr, int* __restrict__ bsums) {
    __shared__ int s[256];
    int t = threadIdx.x;
    int i = blockIdx.x * 256 + t;
    int v = (i < N) ? deg[i] : 0;
    s[t] = v;
    __syncthreads();
    for (int off = 1; off < 256; off <<= 1) {
        int x = (t >= off) ? s[t - off] : 0;
        __syncthreads();
        s[t] += x;
        __syncthreads();
    }
    if (i < N) row_ptr[i] = s[t] - v;           // exclusive
    if (t == 255) bsums[blockIdx.x] = s[255];
}

// Single-block exclusive scan of block sums.
__global__ void scan_top_kernel(const int* __restrict__ in, int n, int* __restrict__ out) {
    __shared__ int s[256];
    int t = threadIdx.x;
    int v = (t < n) ? in[t] : 0;
    s[t] = v;
    __syncthreads();
    for (int off = 1; off < 256; off <<= 1) {
        int x = (t >= off) ? s[t - off] : 0;
        __syncthreads();
        s[t] += x;
        __syncthreads();
    }
    if (t < n) out[t] = s[t] - v;
}

__global__ void finalize_kernel(const int* __restrict__ deg, const int* __restrict__ boffs,
                                int N, int E, int* __restrict__ row_ptr,
                                int* __restrict__ cursor, float* __restrict__ dinv) {
    int i = blockIdx.x * 256 + threadIdx.x;
    if (i < N) {
        int rp = row_ptr[i] + boffs[i >> 8];
        row_ptr[i] = rp;
        cursor[i] = rp;
        dinv[i] = rsqrtf((float)(deg[i] + 1));  // +1 self loop
        if (i == 0) row_ptr[N] = E;
    }
}

__global__ void fill_kernel(const int* __restrict__ ei, int E,
                            int* __restrict__ cursor, int* __restrict__ csr_src) {
    int e = blockIdx.x * 256 + threadIdx.x;
    if (e < E) {
        int dst = ei[E + e];
        int pos = atomicAdd(&cursor[dst], 1);
        csr_src[pos] = ei[e];                   // src = ei[0][e]
    }
}

// ---------------------------------------------------------------------------
// fp32 GEMM: C[N x DO] = A[N x DI] @ W[DI x DO].  256 thr, 4x4 register tile,
// k-tiled (KT=64) LDS staging for both A and W.  Stays under 64 KiB LDS.
// ---------------------------------------------------------------------------
template <int DI, int DO>
__global__ __launch_bounds__(256) void gemm_kernel(const float* __restrict__ A,
                                                   const float* __restrict__ W,
                                                   float* __restrict__ C, int N) {
    constexpr int TC = DO / 4;       // thread-cols
    constexpr int TRG = 256 / TC;    // thread row-groups
    constexpr int ROWS = TRG * 4;    // rows per block
    constexpr int KT = 64;
    constexpr int ALD = KT + 1;      // pad to break bank aliasing
    __shared__ float Wl[KT * DO];
    __shared__ float Al[ROWS * ALD];

    int t = threadIdx.x;
    int r0 = blockIdx.x * ROWS;
    int cg = (t % TC) * 4;
    int rg = (t / TC) * 4;
    float acc[4][4] = {};

    for (int kt = 0; kt < DI; kt += KT) {
        // stage W[kt..kt+KT][:] (contiguous)
        for (int idx = t * 4; idx < KT * DO; idx += 1024)
            *(float4*)&Wl[idx] = *(const float4*)&W[kt * DO + idx];
        // stage A tile
        for (int idx = t; idx < ROWS * KT; idx += 256) {
            int r = idx / KT, c = idx % KT;
            int g = r0 + r;
            Al[r * ALD + c] = (g < N) ? A[(size_t)g * DI + kt + c] : 0.0f;
        }
        __syncthreads();
#pragma unroll 8
        for (int k = 0; k < KT; ++k) {
            float4 w = *(float4*)&Wl[k * DO + cg];
            float a0 = Al[(rg + 0) * ALD + k];
            float a1 = Al[(rg + 1) * ALD + k];
            float a2 = Al[(rg + 2) * ALD + k];
            float a3 = Al[(rg + 3) * ALD + k];
            acc[0][0] += a0 * w.x; acc[0][1] += a0 * w.y; acc[0][2] += a0 * w.z; acc[0][3] += a0 * w.w;
            acc[1][0] += a1 * w.x; acc[1][1] += a1 * w.y; acc[1][2] += a1 * w.z; acc[1][3] += a1 * w.w;
            acc[2][0] += a2 * w.x; acc[2][1] += a2 * w.y; acc[2][2] += a2 * w.z; acc[2][3] += a2 * w.w;
            acc[3][0] += a3 * w.x; acc[3][1] += a3 * w.y; acc[3][2] += a3 * w.z; acc[3][3] += a3 * w.w;
        }
        __syncthreads();
    }
#pragma unroll
    for (int i = 0; i < 4; ++i) {
        int g = r0 + rg + i;
        if (g < N) {
            float4 o = make_float4(acc[i][0], acc[i][1], acc[i][2], acc[i][3]);
            *(float4*)&C[(size_t)g * DO + cg] = o;
        }
    }
}

// ---------------------------------------------------------------------------
// Aggregation: out[i] = relu( dinv[i] * ( dinv[i]*tmp[i] + sum_src dinv[src]*tmp[src] ) + b )
// One wave per node, lane = feature (D=64) or feature & feature+64 (D=128).
// ---------------------------------------------------------------------------
template <int D>
__global__ __launch_bounds__(256) void agg_kernel(const float* __restrict__ tmp,
                                                  const float* __restrict__ bias,
                                                  const float* __restrict__ dinv,
                                                  const int* __restrict__ row_ptr,
                                                  const int* __restrict__ csr_src,
                                                  float* __restrict__ out, int N) {
    int lane = threadIdx.x & 63;
    int node = blockIdx.x * 4 + (threadIdx.x >> 6);
    if (node >= N) return;
    float dvi = dinv[node];
    float acc0 = dvi * tmp[(size_t)node * D + lane];
    float acc1 = 0.0f;
    if (D == 128) acc1 = dvi * tmp[(size_t)node * D + 64 + lane];
    int beg = row_ptr[node], end = row_ptr[node + 1];
    for (int j = beg; j < end; j += 64) {
        int m = end - j;
        if (m > 64) m = 64;
        int s = 0;
        float dv = 0.0f;
        if (lane < m) {
            s = csr_src[j + lane];
            dv = dinv[s];
        }
        for (int k = 0; k < m; ++k) {
            int sk = __shfl(s, k, 64);
            float dvk = __shfl(dv, k, 64);
            acc0 += dvk * tmp[(size_t)sk * D + lane];
            if (D == 128) acc1 += dvk * tmp[(size_t)sk * D + 64 + lane];
        }
    }
    float r0 = dvi * acc0 + bias[lane];
    out[(size_t)node * D + lane] = r0 > 0.0f ? r0 : 0.0f;
    if (D == 128) {
        float r1 = dvi * acc1 + bias[64 + lane];
        out[(size_t)node * D + 64 + lane] = r1 > 0.0f ? r1 : 0.0f;
    }
}

// ---------------------------------------------------------------------------
// Head: prototype distances -> sim -> MLP(16->8->1, exact GELU) -> sigmoid.
// 64 nodes per block; also emits y as float.
// ---------------------------------------------------------------------------
__global__ __launch_bounds__(256) void head_kernel(const float* __restrict__ h,
                                                   const float* __restrict__ protos,
                                                   const float* __restrict__ Wf0,
                                                   const float* __restrict__ bf0,
                                                   const float* __restrict__ Wf1,
                                                   const float* __restrict__ bf1,
                                                   const int* __restrict__ y,
                                                   float* __restrict__ out, int N) {
    __shared__ float Hl[64 * 65];
    __shared__ float Pl[16 * 65];
    __shared__ float hh[64];
    __shared__ float pp[16];
    __shared__ float sim[64 * 17];
    __shared__ float Wf0l[128];
    __shared__ float bf0l[8];
    __shared__ float Wf1l[8];
    __shared__ float bf1l;
    int t = threadIdx.x;
    int n0 = blockIdx.x * 64;

    for (int idx = t; idx < 64 * 64; idx += 256) {
        int r = idx >> 6, c = idx & 63;
        int g = n0 + r;
        Hl[r * 65 + c] = (g < N) ? h[(size_t)g * 64 + c] : 0.0f;
    }
    for (int idx = t; idx < 16 * 64; idx += 256) {
        int r = idx >> 6, c = idx & 63;
        Pl[r * 65 + c] = protos[idx];
    }
    if (t < 128) Wf0l[t] = Wf0[t];
    if (t < 8) { bf0l[t] = bf0[t]; Wf1l[t] = Wf1[t]; }
    if (t == 0) bf1l = bf1[0];
    __syncthreads();

    if (t < 64) {
        float s = 0.0f;
        for (int k = 0; k < 64; ++k) { float v = Hl[t * 65 + k]; s += v * v; }
        hh[t] = s;
    } else if (t < 80) {
        int p = t - 64;
        float s = 0.0f;
        for (int k = 0; k < 64; ++k) { float v = Pl[p * 65 + k]; s += v * v; }
        pp[p] = s;
    }
    __syncthreads();

    {
        int node = t & 63;
        int p4 = (t >> 6) * 4;
        float d0 = 0, d1 = 0, d2 = 0, d3 = 0;
        for (int k = 0; k < 64; ++k) {
            float hv = Hl[node * 65 + k];
            d0 += hv * Pl[(p4 + 0) * 65 + k];
            d1 += hv * Pl[(p4 + 1) * 65 + k];
            d2 += hv * Pl[(p4 + 2) * 65 + k];
            d3 += hv * Pl[(p4 + 3) * 65 + k];
        }
        float hhv = hh[node];
        float dd[4] = {d0, d1, d2, d3};
#pragma unroll
        for (int j = 0; j < 4; ++j) {
            float q = hhv + pp[p4 + j] - 2.0f * dd[j];
            q = q > 0.0f ? q : 0.0f;
            sim[node * 17 + p4 + j] = logf((q + 1.0f) / (q + 1e-4f));
        }
    }
    __syncthreads();

    if (t < 64) {
        int g = n0 + t;
        if (g < N) {
            float zacc = bf1l;
#pragma unroll
            for (int o = 0; o < 8; ++o) {
                float s = bf0l[o];
#pragma unroll
                for (int i2 = 0; i2 < 16; ++i2) s += sim[t * 17 + i2] * Wf0l[i2 * 8 + o];
                float gz = 0.5f * s * (1.0f + erff(s * 0.70710678118654752f));  // exact GELU
                zacc += gz * Wf1l[o];
            }
            out[g] = 1.0f / (1.0f + expf(-zacc));
        }
    } else if (t < 128) {
        int g = n0 + (t - 64);
        if (g < N) out[N + g] = (float)y[g];
    }
}

// ---------------------------------------------------------------------------

extern "C" void kernel_launch(void* const* d_in, const int* in_sizes, int n_in,
                              void* d_out, int out_size, void* d_ws, size_t ws_size,
                              hipStream_t stream) {
    const float* x   = (const float*)d_in[0];
    const int*   ei  = (const int*)d_in[1];
    const int*   y   = (const int*)d_in[2];
    const float* W1  = (const float*)d_in[3];
    const float* b1  = (const float*)d_in[4];
    const float* W2  = (const float*)d_in[5];
    const float* b2  = (const float*)d_in[6];
    const float* W3  = (const float*)d_in[7];
    const float* b3  = (const float*)d_in[8];
    const float* pr  = (const float*)d_in[9];
    const float* Wf0 = (const float*)d_in[10];
    const float* bf0 = (const float*)d_in[11];
    const float* Wf1 = (const float*)d_in[12];
    const float* bf1 = (const float*)d_in[13];
    float* outp = (float*)d_out;

    const int N = in_sizes[2];       // 50000
    const int E = in_sizes[1] / 2;   // 800000

    // workspace carve (512B aligned)
    char* w = (char*)d_ws;
    auto carve = [&](size_t bytes) {
        char* p = w;
        w += (bytes + 511) & ~(size_t)511;
        return p;
    };
    int*   deg     = (int*)carve((size_t)N * 4);
    int*   row_ptr = (int*)carve((size_t)(N + 1) * 4);
    int*   cursor  = (int*)carve((size_t)N * 4);
    int*   bsums   = (int*)carve(256 * 4);
    int*   boffs   = (int*)carve(256 * 4);
    float* dinv    = (float*)carve((size_t)N * 4);
    int*   csr     = (int*)carve((size_t)E * 4);
    float* bufT    = (float*)carve((size_t)N * 128 * 4);
    float* bufH    = (float*)carve((size_t)N * 128 * 4);

    const int nbN = (N + 255) / 256;
    const int nbE = (E + 255) / 256;

    zero_int_kernel<<<nbN, 256, 0, stream>>>(deg, N);
    count_kernel<<<nbE, 256, 0, stream>>>(ei, E, deg);
    scan_block_kernel<<<nbN, 256, 0, stream>>>(deg, N, row_ptr, bsums);
    scan_top_kernel<<<1, 256, 0, stream>>>(bsums, nbN, boffs);
    finalize_kernel<<<nbN, 256, 0, stream>>>(deg, boffs, N, E, row_ptr, cursor, dinv);
    fill_kernel<<<nbE, 256, 0, stream>>>(ei, E, cursor, csr);

    // L1: x(128) @ W1(128x128) -> agg(128)
    gemm_kernel<128, 128><<<(N + 31) / 32, 256, 0, stream>>>(x, W1, bufT, N);
    agg_kernel<128><<<(N + 3) / 4, 256, 0, stream>>>(bufT, b1, dinv, row_ptr, csr, bufH, N);
    // L2: h1(128) @ W2(128x64) -> agg(64)
    gemm_kernel<128, 64><<<(N + 63) / 64, 256, 0, stream>>>(bufH, W2, bufT, N);
    agg_kernel<64><<<(N + 3) / 4, 256, 0, stream>>>(bufT, b2, dinv, row_ptr, csr, bufH, N);
    // L3: h2(64) @ W3(64x64) -> agg(64)
    gemm_kernel<64, 64><<<(N + 63) / 64, 256, 0, stream>>>(bufH, W3, bufT, N);
    agg_kernel<64><<<(N + 3) / 4, 256, 0, stream>>>(bufT, b3, dinv, row_ptr, csr, bufH, N);
    // Head
    head_kernel<<<(N + 63) / 64, 256, 0, stream>>>(bufH, pr, Wf0, bf0, Wf1, bf1, y, outp, N);
}

// Round 2
// 366.738 us; speedup vs baseline: 1.2233x; 1.2233x over previous
//
#include <hip/hip_runtime.h>
#include <hip/hip_bf16.h>
#include <math.h>

// ---------------------------------------------------------------------------
// SLADGNN: 3-layer GCN + prototype head. Round 2: bf16 payload on the heavy
// path (halves gather traffic), MFMA bf16 GEMMs with pre-packed W fragments.
// CSR built by dst once per launch; fp32 accumulation everywhere.
// ---------------------------------------------------------------------------

typedef __attribute__((ext_vector_type(8))) short short8;
typedef __attribute__((ext_vector_type(4))) float f32x4;

__device__ __forceinline__ short f2bs(float x) {
    __hip_bfloat16 b = __float2bfloat16(x);
    return *reinterpret_cast<short*>(&b);
}
__device__ __forceinline__ float2 bpair(unsigned u) {
    float lo = __uint_as_float(u << 16);
    float hi = __uint_as_float(u & 0xffff0000u);
    return make_float2(lo, hi);
}
__device__ __forceinline__ unsigned packbf(float a, float b) {
    unsigned la = (unsigned)(unsigned short)f2bs(a);
    unsigned hb = (unsigned)(unsigned short)f2bs(b);
    return la | (hb << 16);
}

// --------------------------- CSR build -------------------------------------

__global__ void zero_int_kernel(int* __restrict__ p, int n) {
    int i = blockIdx.x * 256 + threadIdx.x;
    if (i < n) p[i] = 0;
}

__global__ void count_kernel(const int* __restrict__ ei, int E, int* __restrict__ deg) {
    int e = blockIdx.x * 256 + threadIdx.x;
    if (e < E) atomicAdd(&deg[ei[E + e]], 1);   // dst = ei[1][e]
}

__global__ void scan_block_kernel(const int* __restrict__ deg, int N,
                                  int* __restrict__ row_ptr, int* __restrict__ bsums) {
    __shared__ int s[256];
    int t = threadIdx.x;
    int i = blockIdx.x * 256 + t;
    int v = (i < N) ? deg[i] : 0;
    s[t] = v;
    __syncthreads();
    for (int off = 1; off < 256; off <<= 1) {
        int x = (t >= off) ? s[t - off] : 0;
        __syncthreads();
        s[t] += x;
        __syncthreads();
    }
    if (i < N) row_ptr[i] = s[t] - v;
    if (t == 255) bsums[blockIdx.x] = s[255];
}

__global__ void scan_top_kernel(const int* __restrict__ in, int n, int* __restrict__ out) {
    __shared__ int s[256];
    int t = threadIdx.x;
    int v = (t < n) ? in[t] : 0;
    s[t] = v;
    __syncthreads();
    for (int off = 1; off < 256; off <<= 1) {
        int x = (t >= off) ? s[t - off] : 0;
        __syncthreads();
        s[t] += x;
        __syncthreads();
    }
    if (t < n) out[t] = s[t] - v;
}

__global__ void finalize_kernel(const int* __restrict__ deg, const int* __restrict__ boffs,
                                int N, int E, int* __restrict__ row_ptr,
                                int* __restrict__ cursor, float* __restrict__ dinv) {
    int i = blockIdx.x * 256 + threadIdx.x;
    if (i < N) {
        int rp = row_ptr[i] + boffs[i >> 8];
        row_ptr[i] = rp;
        cursor[i] = rp;
        dinv[i] = rsqrtf((float)(deg[i] + 1));  // +1 self loop
        if (i == 0) row_ptr[N] = E;
    }
}

__global__ void fill_kernel(const int* __restrict__ ei, int E,
                            int* __restrict__ cursor, int* __restrict__ csr_src) {
    int e = blockIdx.x * 256 + threadIdx.x;
    if (e < E) {
        int dst = ei[E + e];
        int pos = atomicAdd(&cursor[dst], 1);
        csr_src[pos] = ei[e];
    }
}

// --------------------------- weight prep -----------------------------------
// Pack W[DI][DO] (fp32, row-major) into B-fragment order: for each k-block of
// 8 and col n, the 8 bf16 {W[kb*8+j][n]} are contiguous -> one 16B lane load.

__global__ void prep_w_kernel(const float* __restrict__ W1, const float* __restrict__ W2,
                              const float* __restrict__ W3,
                              __hip_bfloat16* __restrict__ Wp1,
                              __hip_bfloat16* __restrict__ Wp2,
                              __hip_bfloat16* __restrict__ Wp3) {
    int i = blockIdx.x * 256 + threadIdx.x;
    if (i < 16384) {                      // W1: 128x128
        int k = i >> 7, n = i & 127;
        Wp1[(((k >> 3) * 128) + n) * 8 + (k & 7)] = __float2bfloat16(W1[i]);
    } else if (i < 24576) {               // W2: 128x64
        int j = i - 16384;
        int k = j >> 6, n = j & 63;
        Wp2[(((k >> 3) * 64) + n) * 8 + (k & 7)] = __float2bfloat16(W2[j]);
    } else if (i < 28672) {               // W3: 64x64
        int j = i - 24576;
        int k = j >> 6, n = j & 63;
        Wp3[(((k >> 3) * 64) + n) * 8 + (k & 7)] = __float2bfloat16(W3[j]);
    }
}

// --------------------------- MFMA GEMM -------------------------------------
// C[N x DO] (bf16) = A[N x DI] @ W[DI x DO]; A fp32 (layer 1) or bf16.
// 4 waves/block, 16 rows/wave, all DO cols per wave. No LDS: A frag is a
// contiguous 16B row chunk; B frag is a 16B chunk of pre-packed Wp.

template <int DI, int DO, bool AF32>
__global__ __launch_bounds__(256) void mfma_gemm_kernel(const void* __restrict__ Av,
                                                        const __hip_bfloat16* __restrict__ Wp,
                                                        __hip_bfloat16* __restrict__ C, int N) {
    constexpr int NT = DO / 16;
    int t = threadIdx.x;
    int wave = t >> 6, lane = t & 63;
    int q = lane >> 4, l16 = lane & 15;
    int rbase = blockIdx.x * 64 + wave * 16;
    int row = rbase + l16;
    int rowc = row < N ? row : N - 1;

    f32x4 acc[NT];
#pragma unroll
    for (int i = 0; i < NT; ++i) acc[i] = (f32x4){0.f, 0.f, 0.f, 0.f};

#pragma unroll
    for (int kt = 0; kt < DI / 32; ++kt) {
        int k0 = kt * 32 + q * 8;
        short8 afrag;
        if (AF32) {
            const float* A = (const float*)Av;
            const float* ap = A + (size_t)rowc * DI + k0;
            float4 lo = *(const float4*)ap;
            float4 hi = *(const float4*)(ap + 4);
            afrag[0] = f2bs(lo.x); afrag[1] = f2bs(lo.y);
            afrag[2] = f2bs(lo.z); afrag[3] = f2bs(lo.w);
            afrag[4] = f2bs(hi.x); afrag[5] = f2bs(hi.y);
            afrag[6] = f2bs(hi.z); afrag[7] = f2bs(hi.w);
        } else {
            const __hip_bfloat16* A = (const __hip_bfloat16*)Av;
            afrag = *(const short8*)(A + (size_t)rowc * DI + k0);
        }
        const short8* wrow = (const short8*)(Wp + (size_t)(kt * 4 + q) * DO * 8);
#pragma unroll
        for (int tt = 0; tt < NT; ++tt) {
            short8 bfrag = wrow[tt * 16 + l16];
            acc[tt] = __builtin_amdgcn_mfma_f32_16x16x32_bf16(afrag, bfrag, acc[tt], 0, 0, 0);
        }
    }
    // C/D layout: col = lane&15, row = (lane>>4)*4 + reg  [m89-verified]
#pragma unroll
    for (int tt = 0; tt < NT; ++tt) {
#pragma unroll
        for (int r = 0; r < 4; ++r) {
            int gr = rbase + q * 4 + r;
            if (gr < N) {
                __hip_bfloat16 v = __float2bfloat16(acc[tt][r]);
                C[(size_t)gr * DO + tt * 16 + l16] = v;
            }
        }
    }
}

// --------------------------- aggregation -----------------------------------
// out[i] = relu( dinv[i]*( dinv[i]*tmp[i] + sum_src dinv[src]*tmp[src] ) + b )
// bf16 rows packed as uint pairs; fp32 accumulation.

// D=128: one node per wave, lane covers features 2*lane, 2*lane+1.
__global__ __launch_bounds__(256) void agg128_kernel(const unsigned* __restrict__ tmp,
                                                     const float* __restrict__ bias,
                                                     const float* __restrict__ dinv,
                                                     const int* __restrict__ row_ptr,
                                                     const int* __restrict__ csr_src,
                                                     unsigned* __restrict__ outp, int N) {
    int lane = threadIdx.x & 63;
    int node = blockIdx.x * 4 + (threadIdx.x >> 6);
    if (node >= N) return;
    float dvi = dinv[node];
    float2 sv = bpair(tmp[(size_t)node * 64 + lane]);
    float acc0 = dvi * sv.x, acc1 = dvi * sv.y;
    int beg = row_ptr[node], end = row_ptr[node + 1];
    for (int j = beg; j < end; j += 64) {
        int m = end - j;
        if (m > 64) m = 64;
        int s = 0;
        float dv = 0.0f;
        if (lane < m) { s = csr_src[j + lane]; dv = dinv[s]; }
        for (int k = 0; k < m; ++k) {
            int sk = __shfl(s, k, 64);
            float dvk = __shfl(dv, k, 64);
            float2 v = bpair(tmp[(size_t)sk * 64 + lane]);
            acc0 += dvk * v.x;
            acc1 += dvk * v.y;
        }
    }
    float2 bb = *(const float2*)&bias[lane * 2];
    float r0 = fmaxf(dvi * acc0 + bb.x, 0.0f);
    float r1 = fmaxf(dvi * acc1 + bb.y, 0.0f);
    outp[(size_t)node * 64 + lane] = packbf(r0, r1);
}

// D=64: one node per wave, half-wave per edge (2 edges/iter), lane covers
// features 2*(lane&31), +1.
__global__ __launch_bounds__(256) void agg64_kernel(const unsigned* __restrict__ tmp,
                                                    const float* __restrict__ bias,
                                                    const float* __restrict__ dinv,
                                                    const int* __restrict__ row_ptr,
                                                    const int* __restrict__ csr_src,
                                                    unsigned* __restrict__ outp, int N) {
    int lane = threadIdx.x & 63;
    int half = lane >> 5, fl = lane & 31;
    int node = blockIdx.x * 4 + (threadIdx.x >> 6);
    if (node >= N) return;
    float dvi = dinv[node];
    float acc0 = 0.0f, acc1 = 0.0f;
    if (half == 0) {
        float2 sv = bpair(tmp[(size_t)node * 32 + fl]);
        acc0 = dvi * sv.x;
        acc1 = dvi * sv.y;
    }
    int beg = row_ptr[node], end = row_ptr[node + 1];
    for (int j = beg; j < end; j += 64) {
        int m = end - j;
        if (m > 64) m = 64;
        int s = 0;
        float dv = 0.0f;
        if (lane < m) { s = csr_src[j + lane]; dv = dinv[s]; }
        int iters = (m + 1) >> 1;
        for (int k = 0; k < iters; ++k) {
            int e = 2 * k + half;
            int ec = e < m ? e : m - 1;
            int sk = __shfl(s, ec, 64);
            float dvk = __shfl(dv, ec, 64);
            float2 v = bpair(tmp[(size_t)sk * 32 + fl]);
            if (e < m) {
                acc0 += dvk * v.x;
                acc1 += dvk * v.y;
            }
        }
    }
    acc0 += __shfl_xor(acc0, 32, 64);
    acc1 += __shfl_xor(acc1, 32, 64);
    if (half == 0) {
        float2 bb = *(const float2*)&bias[fl * 2];
        float r0 = fmaxf(dvi * acc0 + bb.x, 0.0f);
        float r1 = fmaxf(dvi * acc1 + bb.y, 0.0f);
        outp[(size_t)node * 32 + fl] = packbf(r0, r1);
    }
}

// --------------------------- head ------------------------------------------

__global__ __launch_bounds__(256) void head_kernel(const unsigned* __restrict__ h,
                                                   const float* __restrict__ protos,
                                                   const float* __restrict__ Wf0,
                                                   const float* __restrict__ bf0,
                                                   const float* __restrict__ Wf1,
                                                   const float* __restrict__ bf1,
                                                   const int* __restrict__ y,
                                                   float* __restrict__ out, int N) {
    __shared__ float Hl[64 * 65];
    __shared__ float Pl[16 * 65];
    __shared__ float hh[64];
    __shared__ float pp[16];
    __shared__ float sim[64 * 17];
    __shared__ float Wf0l[128];
    __shared__ float bf0l[8];
    __shared__ float Wf1l[8];
    __shared__ float bf1l;
    int t = threadIdx.x;
    int n0 = blockIdx.x * 64;

    for (int idx = t; idx < 64 * 32; idx += 256) {
        int r = idx >> 5, c = idx & 31;
        int g = n0 + r;
        unsigned u = (g < N) ? h[(size_t)g * 32 + c] : 0u;
        float2 v = bpair(u);
        Hl[r * 65 + 2 * c] = v.x;
        Hl[r * 65 + 2 * c + 1] = v.y;
    }
    for (int idx = t; idx < 16 * 64; idx += 256) {
        int r = idx >> 6, c = idx & 63;
        Pl[r * 65 + c] = protos[idx];
    }
    if (t < 128) Wf0l[t] = Wf0[t];
    if (t < 8) { bf0l[t] = bf0[t]; Wf1l[t] = Wf1[t]; }
    if (t == 0) bf1l = bf1[0];
    __syncthreads();

    if (t < 64) {
        float s = 0.0f;
        for (int k = 0; k < 64; ++k) { float v = Hl[t * 65 + k]; s += v * v; }
        hh[t] = s;
    } else if (t < 80) {
        int p = t - 64;
        float s = 0.0f;
        for (int k = 0; k < 64; ++k) { float v = Pl[p * 65 + k]; s += v * v; }
        pp[p] = s;
    }
    __syncthreads();

    {
        int node = t & 63;
        int p4 = (t >> 6) * 4;
        float d0 = 0, d1 = 0, d2 = 0, d3 = 0;
        for (int k = 0; k < 64; ++k) {
            float hv = Hl[node * 65 + k];
            d0 += hv * Pl[(p4 + 0) * 65 + k];
            d1 += hv * Pl[(p4 + 1) * 65 + k];
            d2 += hv * Pl[(p4 + 2) * 65 + k];
            d3 += hv * Pl[(p4 + 3) * 65 + k];
        }
        float hhv = hh[node];
        float dd[4] = {d0, d1, d2, d3};
#pragma unroll
        for (int j = 0; j < 4; ++j) {
            float q = hhv + pp[p4 + j] - 2.0f * dd[j];
            q = q > 0.0f ? q : 0.0f;
            sim[node * 17 + p4 + j] = logf((q + 1.0f) / (q + 1e-4f));
        }
    }
    __syncthreads();

    if (t < 64) {
        int g = n0 + t;
        if (g < N) {
            float zacc = bf1l;
#pragma unroll
            for (int o = 0; o < 8; ++o) {
                float s = bf0l[o];
#pragma unroll
                for (int i2 = 0; i2 < 16; ++i2) s += sim[t * 17 + i2] * Wf0l[i2 * 8 + o];
                float gz = 0.5f * s * (1.0f + erff(s * 0.70710678118654752f));
                zacc += gz * Wf1l[o];
            }
            out[g] = 1.0f / (1.0f + expf(-zacc));
        }
    } else if (t < 128) {
        int g = n0 + (t - 64);
        if (g < N) out[N + g] = (float)y[g];
    }
}

// ---------------------------------------------------------------------------

extern "C" void kernel_launch(void* const* d_in, const int* in_sizes, int n_in,
                              void* d_out, int out_size, void* d_ws, size_t ws_size,
                              hipStream_t stream) {
    const float* x   = (const float*)d_in[0];
    const int*   ei  = (const int*)d_in[1];
    const int*   y   = (const int*)d_in[2];
    const float* W1  = (const float*)d_in[3];
    const float* b1  = (const float*)d_in[4];
    const float* W2  = (const float*)d_in[5];
    const float* b2  = (const float*)d_in[6];
    const float* W3  = (const float*)d_in[7];
    const float* b3  = (const float*)d_in[8];
    const float* pr  = (const float*)d_in[9];
    const float* Wf0 = (const float*)d_in[10];
    const float* bf0 = (const float*)d_in[11];
    const float* Wf1 = (const float*)d_in[12];
    const float* bf1 = (const float*)d_in[13];
    float* outp = (float*)d_out;

    const int N = in_sizes[2];       // 50000
    const int E = in_sizes[1] / 2;   // 800000

    char* w = (char*)d_ws;
    auto carve = [&](size_t bytes) {
        char* p = w;
        w += (bytes + 511) & ~(size_t)511;
        return p;
    };
    int*   deg     = (int*)carve((size_t)N * 4);
    int*   row_ptr = (int*)carve((size_t)(N + 1) * 4);
    int*   cursor  = (int*)carve((size_t)N * 4);
    int*   bsums   = (int*)carve(256 * 4);
    int*   boffs   = (int*)carve(256 * 4);
    float* dinv    = (float*)carve((size_t)N * 4);
    int*   csr     = (int*)carve((size_t)E * 4);
    __hip_bfloat16* Wp1 = (__hip_bfloat16*)carve(16384 * 2);
    __hip_bfloat16* Wp2 = (__hip_bfloat16*)carve(8192 * 2);
    __hip_bfloat16* Wp3 = (__hip_bfloat16*)carve(4096 * 2);
    __hip_bfloat16* bufT = (__hip_bfloat16*)carve((size_t)N * 128 * 2);
    __hip_bfloat16* bufH = (__hip_bfloat16*)carve((size_t)N * 128 * 2);

    const int nbN = (N + 255) / 256;
    const int nbE = (E + 255) / 256;

    zero_int_kernel<<<nbN, 256, 0, stream>>>(deg, N);
    count_kernel<<<nbE, 256, 0, stream>>>(ei, E, deg);
    scan_block_kernel<<<nbN, 256, 0, stream>>>(deg, N, row_ptr, bsums);
    scan_top_kernel<<<1, 256, 0, stream>>>(bsums, nbN, boffs);
    finalize_kernel<<<nbN, 256, 0, stream>>>(deg, boffs, N, E, row_ptr, cursor, dinv);
    fill_kernel<<<nbE, 256, 0, stream>>>(ei, E, cursor, csr);
    prep_w_kernel<<<(28672 + 255) / 256, 256, 0, stream>>>(W1, W2, W3, Wp1, Wp2, Wp3);

    // L1: x(f32,128) @ W1 -> bufT(bf16,128); agg128 -> bufH
    mfma_gemm_kernel<128, 128, true><<<(N + 63) / 64, 256, 0, stream>>>(x, Wp1, bufT, N);
    agg128_kernel<<<(N + 3) / 4, 256, 0, stream>>>((const unsigned*)bufT, b1, dinv, row_ptr, csr,
                                                   (unsigned*)bufH, N);
    // L2: bufH(bf16,128) @ W2 -> bufT(bf16,64); agg64 -> bufH
    mfma_gemm_kernel<128, 64, false><<<(N + 63) / 64, 256, 0, stream>>>(bufH, Wp2, bufT, N);
    agg64_kernel<<<(N + 3) / 4, 256, 0, stream>>>((const unsigned*)bufT, b2, dinv, row_ptr, csr,
                                                  (unsigned*)bufH, N);
    // L3: bufH(bf16,64) @ W3 -> bufT(bf16,64); agg64 -> bufH
    mfma_gemm_kernel<64, 64, false><<<(N + 63) / 64, 256, 0, stream>>>(bufH, Wp3, bufT, N);
    agg64_kernel<<<(N + 3) / 4, 256, 0, stream>>>((const unsigned*)bufT, b3, dinv, row_ptr, csr,
                                                  (unsigned*)bufH, N);
    // Head
    head_kernel<<<(N + 63) / 64, 256, 0, stream>>>((const unsigned*)bufH, pr, Wf0, bf0, Wf1, bf1,
                                                   y, outp, N);
}